// Round 20
// baseline (214.479 us; speedup 1.0000x reference)
//
#include <hip/hip_runtime.h>

// Node_Edge_Switch_Attention on MI355X (gfx950)
// R20 = R19 (186.1us best) + two extensions of the proven levers:
//   (1) proj_q merged into proj_kv -> single proj_all launch (768 blocks,
//       block-uniform range decode, template-cloned bodies -- R19 pattern).
//   (2) cvtW eliminated: W converted fp32->bf16 in-register (same RTNE, bit-identical)
//       inside proj_body and proj_out. Launches 7 -> 5 (~2 fewer gaps + cvtW time).
// tgemm/finalize/attn byte-identical to R19. ws: wbf dropped.

#define N_NODES 4096
#define N_EDGES 16384
#define HIDDEN  256
#define KSPLIT  16

typedef __attribute__((ext_vector_type(4))) float f32x4;
typedef __attribute__((ext_vector_type(8))) short s16x8;          // 8 bf16 (4 VGPRs)
typedef __attribute__((ext_vector_type(4))) unsigned short u16x4;
typedef __attribute__((ext_vector_type(8))) unsigned short u16x8;

__device__ __forceinline__ unsigned short f2bf(float f) {
    union { float f; unsigned u; } x; x.f = f;
    unsigned r = x.u + 0x7FFFu + ((x.u >> 16) & 1u);   // RTNE (values finite here)
    return (unsigned short)(r >> 16);
}
__device__ __forceinline__ float bf2f(unsigned short u) {
    union { unsigned u; float f; } x; x.u = (unsigned)u << 16; return x.f;
}
__device__ __forceinline__ s16x8 pack8s(f32x4 x, f32x4 y) {
    u16x8 o;
    o[0]=f2bf(x[0]); o[1]=f2bf(x[1]); o[2]=f2bf(x[2]); o[3]=f2bf(x[3]);
    o[4]=f2bf(y[0]); o[5]=f2bf(y[1]); o[6]=f2bf(y[2]); o[7]=f2bf(y[3]);
    union { u16x8 u; s16x8 s; } c; c.u = o; return c.s;
}

// ---------------- shared projection core (fp32 W, in-reg convert) -------------------
// One 64(m) x 128(n) tile: af loaded once, bn-loop of 2. MODE1 row-major out;
// MODE2 transposed out via LDS 64x64 tile (pad 68) -> 32B-contiguous stores.
template<int MODE>
__device__ __forceinline__
void proj_body(const float* __restrict__ A, const float* __restrict__ W,
               const float* __restrict__ bias, unsigned short* __restrict__ out,
               int M, int mb, int ny)
{
    __shared__ __align__(16) unsigned short Tt[64][68];   // MODE2 transpose tile
    const int t = threadIdx.x;
    const int w = t >> 6, l = t & 63, lo = l & 15, h4 = l >> 4;
    const int m0 = mb + w * 16;
    const float* Ar = A + (long)(m0 + lo) * 256 + h4 * 8;

    s16x8 af[8];
    #pragma unroll
    for (int kk = 0; kk < 8; ++kk) {
        f32x4 x = *(const f32x4*)&Ar[kk * 32];
        f32x4 y = *(const f32x4*)&Ar[kk * 32 + 4];
        af[kk] = pack8s(x, y);
    }
    #pragma unroll
    for (int bi = 0; bi < 2; ++bi) {
        const int bn = ny * 128 + bi * 64;
        f32x4 acc[4] = {};
        #pragma unroll
        for (int kk = 0; kk < 8; ++kk)
            #pragma unroll
            for (int nj = 0; nj < 4; ++nj) {
                const float* Wr = &W[(bn + nj * 16 + lo) * 256 + kk * 32 + h4 * 8];
                f32x4 wx = *(const f32x4*)&Wr[0];
                f32x4 wy = *(const f32x4*)&Wr[4];
                acc[nj] = __builtin_amdgcn_mfma_f32_16x16x32_bf16(af[kk], pack8s(wx, wy),
                                                                  acc[nj], 0, 0, 0);
            }
        if (MODE == 1) {
            #pragma unroll
            for (int nj = 0; nj < 4; ++nj) {
                const int n = bn + nj * 16 + lo;
                const float bi_ = bias[n];
                #pragma unroll
                for (int r = 0; r < 4; ++r)
                    out[(long)(m0 + h4 * 4 + r) * 256 + n] = f2bf(acc[nj][r] + bi_);
            }
        } else {
            if (bi) __syncthreads();                   // prior tile's reads done
            #pragma unroll
            for (int nj = 0; nj < 4; ++nj) {
                const int nl = nj * 16 + lo;
                const float bi_ = bias[bn + nl];
                u16x4 o;
                #pragma unroll
                for (int r = 0; r < 4; ++r) o[r] = f2bf(acc[nj][r] + bi_);
                *(u16x4*)&Tt[nl][w * 16 + h4 * 4] = o;
            }
            __syncthreads();                           // tile complete in LDS
            const int row = t >> 2, seg = (t & 3) * 16;
            u16x8 lo8 = *(const u16x8*)&Tt[row][seg];
            u16x8 hi8 = *(const u16x8*)&Tt[row][seg + 8];
            unsigned short* dst = &out[(long)(bn + row) * M + mb + seg];
            *(u16x8*)dst        = lo8;
            *(u16x8*)(dst + 8)  = hi8;
        }
    }
}

// all three input projections in one launch; block-uniform range decode.
// blocks [0,512): q (MODE2, M=16384; x=bid&255, ny=bid>>8)
// blocks [512,768): b2=bid-512: x=b2&63, y=b2>>6; y>>1 ? v(MODE2) : k(MODE1); ny=y&1
__global__ __launch_bounds__(256)
void proj_all(const float* __restrict__ q, const float* __restrict__ k,
              const float* __restrict__ v,
              const float* __restrict__ Wq, const float* __restrict__ bq,
              const float* __restrict__ Wk, const float* __restrict__ bk,
              const float* __restrict__ Wv, const float* __restrict__ bv,
              unsigned short* __restrict__ qh_t, unsigned short* __restrict__ kh,
              unsigned short* __restrict__ vh_t)
{
    const int bid = blockIdx.x;
    if (bid < 512) {
        proj_body<2>(q, Wq, bq, qh_t, N_EDGES, (bid & 255) * 64, bid >> 8);
    } else {
        const int b2 = bid - 512;
        const int mbx = (b2 & 63) * 64, y = b2 >> 6, ny = y & 1;
        if ((y >> 1) == 0) proj_body<1>(k, Wk, bk, kh,   N_NODES, mbx, ny);
        else               proj_body<2>(v, Wv, bv, vh_t, N_NODES, mbx, ny);
    }
}

// ---------------- out-proj MFMA, 4-way merge from bf16 pctx, fp32 Wo in-reg ---------
__global__ __launch_bounds__(256)
void proj_out_mfma(const unsigned short* __restrict__ pctx, const float* __restrict__ plp,
                   const float* __restrict__ Wo, const float* __restrict__ bo,
                   float* __restrict__ out)
{
    const int t = threadIdx.x;
    const int w = t >> 6, l = t & 63, lo = l & 15, h4 = l >> 4;
    const int m0 = blockIdx.x * 64 + w * 16;
    const int bn = blockIdx.y * 64;
    const int m = m0 + lo;

    float inv[8];
    #pragma unroll
    for (int h = 0; h < 8; ++h) {
        float s = plp[(0 * 8 + h) * N_NODES + m] + plp[(1 * 8 + h) * N_NODES + m]
                + plp[(2 * 8 + h) * N_NODES + m] + plp[(3 * 8 + h) * N_NODES + m];
        inv[h] = 1.0f / s;
    }
    const unsigned short* P = pctx + (long)m * 256;
    const long PS = (long)N_NODES * 256;

    f32x4 acc[4] = {};
    #pragma unroll
    for (int kk = 0; kk < 8; ++kk) {
        const int off = kk * 32 + h4 * 8;
        f32x4 x = {}, y = {};
        #pragma unroll
        for (int p = 0; p < 4; ++p) {
            u16x8 vv = *(const u16x8*)&P[p * PS + off];
            #pragma unroll
            for (int i = 0; i < 4; ++i) { x[i] += bf2f(vv[i]); y[i] += bf2f(vv[i + 4]); }
        }
        s16x8 af = pack8s(x * inv[kk], y * inv[kk]);
        #pragma unroll
        for (int nj = 0; nj < 4; ++nj) {
            const float* Wr = &Wo[(bn + nj * 16 + lo) * 256 + off];
            f32x4 wx = *(const f32x4*)&Wr[0];
            f32x4 wy = *(const f32x4*)&Wr[4];
            acc[nj] = __builtin_amdgcn_mfma_f32_16x16x32_bf16(af, pack8s(wx, wy),
                                                              acc[nj], 0, 0, 0);
        }
    }
    #pragma unroll
    for (int nj = 0; nj < 4; ++nj) {
        const int n = bn + nj * 16 + lo;
        const float bi = bo[n];
        #pragma unroll
        for (int r = 0; r < 4; ++r)
            out[(long)(m0 + h4 * 4 + r) * 256 + n] = acc[nj][r] + bi;
    }
}

// ---------------- T @ qh_t^T : 128-row tile, split-K=16, counted-vmcnt (R19-exact) --
__global__ __launch_bounds__(512, 4)
void tgemm(const float* __restrict__ T, const unsigned short* __restrict__ Bt,
           unsigned short* __restrict__ part, float* __restrict__ rsp)
{
    __shared__ __align__(16) unsigned short Bsm[2][256 * 64];   // 32 KB each
    const int t  = threadIdx.x;
    const int ks = blockIdx.x & 15, ms = blockIdx.x >> 4;
    const int m0 = ms * 128;
    const long k00 = (long)ks * 1024;
    const int w = t >> 6, l = t & 63, lo = l & 15, h4 = l >> 4;

    const int kx = ((l & 7) * 8) ^ ((l >> 3) << 3);            // ushort units
    const unsigned short* Bsrc = Bt + k00 + kx;

#define STAGE(itv, bufv) do {                                                       \
    const unsigned short* _s = Bsrc + (long)(itv) * 64;                             \
    unsigned short* _d = &Bsm[(bufv)][w * 2048];                                    \
    _Pragma("unroll")                                                               \
    for (int _i = 0; _i < 4; ++_i)                                                  \
        __builtin_amdgcn_global_load_lds(                                           \
            (const __attribute__((address_space(1))) unsigned int*)                 \
                (_s + (long)(w * 32 + _i * 8 + (l >> 3)) * N_EDGES),                \
            (__attribute__((address_space(3))) unsigned int*)(_d + _i * 512),       \
            16, 0, 0);                                                              \
} while (0)

    const float* Arow = T + (long)(m0 + w * 16 + lo) * N_EDGES + k00 + h4 * 8;

    f32x4 a0 = *(const f32x4*)&Arow[0];
    f32x4 a1 = *(const f32x4*)&Arow[4];
    f32x4 a2 = *(const f32x4*)&Arow[32];
    f32x4 a3 = *(const f32x4*)&Arow[36];
    STAGE(0, 0);

    f32x4 acc[16] = {};
    float rs = 0.f;

    for (int it = 0; it < 16; ++it) {
        const int cur = it & 1;
        __builtin_amdgcn_s_barrier();                // WAR: all waves done reading buf cur^1
        if (it < 15) {
            STAGE(it + 1, cur ^ 1);                  // 4 VMEM (newest)
            asm volatile("s_waitcnt vmcnt(4)" ::: "memory");   // stage(it)+A(it) landed
        } else {
            asm volatile("s_waitcnt vmcnt(0)" ::: "memory");   // final iter: full drain
        }
        s16x8 af0 = pack8s(a0, a1);                  // consume a BEFORE overwrite
        s16x8 af1 = pack8s(a2, a3);
        rs += a0[0]+a0[1]+a0[2]+a0[3] + a1[0]+a1[1]+a1[2]+a1[3]
            + a2[0]+a2[1]+a2[2]+a2[3] + a3[0]+a3[1]+a3[2]+a3[3];
        if (it < 15) {                               // A prefetch (4 VMEM, same bank)
            const float* An = Arow + (it + 1) * 64;
            a0 = *(const f32x4*)&An[0];
            a1 = *(const f32x4*)&An[4];
            a2 = *(const f32x4*)&An[32];
            a3 = *(const f32x4*)&An[36];
        }
        __builtin_amdgcn_s_barrier();                // RAW: every wave's stage(it) in LDS
        __builtin_amdgcn_sched_barrier(0);           // no ds_read hoisted above barrier

        const unsigned short* Bb = Bsm[cur];
        const int swz = (lo & 7) << 3;               // ushort units
        #pragma unroll
        for (int nj = 0; nj < 16; ++nj) {
            const int jb = (nj * 16 + lo) * 64;
            s16x8 bf0 = *(const s16x8*)&Bb[jb + ((h4 * 8) ^ swz)];
            s16x8 bf1 = *(const s16x8*)&Bb[jb + ((32 + h4 * 8) ^ swz)];
            acc[nj] = __builtin_amdgcn_mfma_f32_16x16x32_bf16(af0, bf0, acc[nj], 0, 0, 0);
            acc[nj] = __builtin_amdgcn_mfma_f32_16x16x32_bf16(af1, bf1, acc[nj], 0, 0, 0);
        }
    }
#undef STAGE

    rs += __shfl_xor(rs, 16); rs += __shfl_xor(rs, 32);
    if (h4 == 0) rsp[ks * N_NODES + m0 + w * 16 + lo] = rs;

    unsigned short* P = part + (long)ks * (N_NODES * HIDDEN);
    #pragma unroll
    for (int nj = 0; nj < 16; ++nj)
        #pragma unroll
        for (int r = 0; r < 4; ++r)
            P[(long)(m0 + w * 16 + h4 * 4 + r) * HIDDEN + nj * 16 + lo] = f2bf(acc[nj][r]);
}

// ---------------- finalize: qn = scale * sum_ks(bf16 part) / rowsum -> bf16 ---------
__global__ __launch_bounds__(256)
void finalize(const unsigned short* __restrict__ part, const float* __restrict__ rsp,
              unsigned short* __restrict__ qn)
{
    const int idx = blockIdx.x * 256 + threadIdx.x;    // 262144 groups of 4
    const long i4 = (long)idx * 4;
    const int n = (int)(i4 >> 8);
    f32x4 s = {};
    #pragma unroll
    for (int ksp = 0; ksp < KSPLIT; ++ksp) {
        u16x4 p = *(const u16x4*)&part[(long)ksp * (N_NODES * HIDDEN) + i4];
        #pragma unroll
        for (int i = 0; i < 4; ++i) s[i] += bf2f(p[i]);
    }
    float rs = 0.f;
    #pragma unroll
    for (int ksp = 0; ksp < KSPLIT; ++ksp) rs += rsp[ksp * N_NODES + n];
    rs = (rs == 0.0f) ? 1.0f : rs;                    // reference zero-row guard
    const float sc = 0.17677669529663687f / rs;       // 32^-0.5
    u16x4 o;
    #pragma unroll
    for (int i = 0; i < 4; ++i) o[i] = f2bf(s[i] * sc);
    *(u16x4*)&qn[i4] = o;
}

// ---------------- attention, m-split x4, K/V reg-prefetch, cvt_pk P, bf16 pctx ------
__global__ __launch_bounds__(256)
void attn(const unsigned short* __restrict__ qn, const unsigned short* __restrict__ kh,
          const unsigned short* __restrict__ vht, unsigned short* __restrict__ pctx,
          float* __restrict__ plp)
{
    __shared__ __align__(16) unsigned short Ksm[64 * 40];       // 80B rows
    __shared__ __align__(16) unsigned short Vsm[32 * 72];       // 144B rows
    __shared__ __align__(16) unsigned short Psm[4][32 * 72];    // per-wave P (bf16)
    const int t  = threadIdx.x;
    const int hh = blockIdx.x >> 7, nb = (blockIdx.x >> 2) & 31, mh = blockIdx.x & 3;
    const int w = t >> 6, l = t & 63, lo = l & 15, h4 = l >> 4;
    const int n0 = nb * 128 + w * 32;

    const int km = t >> 2, kdc = (t & 3) * 8;
    const int vd = t >> 3, vmc = (t & 7) * 8;

    s16x8 qf[2];
    #pragma unroll
    for (int ni = 0; ni < 2; ++ni)
        qf[ni] = *(const s16x8*)&qn[(long)(n0 + ni * 16 + lo) * HIDDEN + hh * 32 + h4 * 8];

    const unsigned short* kp = &kh[(long)(mh * 1024 + km) * HIDDEN + hh * 32 + kdc];
    const unsigned short* vp = &vht[(long)(hh * 32 + vd) * N_NODES + mh * 1024 + vmc];
    s16x8 kreg = *(const s16x8*)kp;
    s16x8 vreg = *(const s16x8*)vp;

    f32x4 acc[2][2] = {};
    float lp[2][4] = {};
    const f32x4 zero = {};

    for (int it = 0; it < 16; ++it) {
        *(s16x8*)&Ksm[km * 40 + kdc] = kreg;
        *(s16x8*)&Vsm[vd * 72 + vmc] = vreg;
        __syncthreads();                      // staging writes visible
        if (it < 15) {                        // prefetch next tile under compute
            kreg = *(const s16x8*)(kp + (long)(it + 1) * 64 * HIDDEN);
            vreg = *(const s16x8*)(vp + (it + 1) * 64);
        }

        s16x8 kb[4];
        #pragma unroll
        for (int mi = 0; mi < 4; ++mi)
            kb[mi] = *(const s16x8*)&Ksm[(mi * 16 + lo) * 40 + h4 * 8];
        #pragma unroll
        for (int ni = 0; ni < 2; ++ni) {
            #pragma unroll
            for (int mi = 0; mi < 4; ++mi) {
                f32x4 s = __builtin_amdgcn_mfma_f32_16x16x32_bf16(qf[ni], kb[mi], zero, 0, 0, 0);
                float p0 = __expf(s[0]), p1 = __expf(s[1]);
                float p2 = __expf(s[2]), p3 = __expf(s[3]);
                lp[ni][0] += p0; lp[ni][1] += p1; lp[ni][2] += p2; lp[ni][3] += p3;
                unsigned pk01, pk23;                  // RTNE, identical to f2bf
                asm("v_cvt_pk_bf16_f32 %0, %1, %2" : "=v"(pk01) : "v"(p0), "v"(p1));
                asm("v_cvt_pk_bf16_f32 %0, %1, %2" : "=v"(pk23) : "v"(p2), "v"(p3));
                const int pb = (ni * 16 + h4 * 4) * 72 + mi * 16 + lo;
                Psm[w][pb]           = (unsigned short)(pk01 & 0xffffu);
                Psm[w][pb + 72]      = (unsigned short)(pk01 >> 16);
                Psm[w][pb + 144]     = (unsigned short)(pk23 & 0xffffu);
                Psm[w][pb + 216]     = (unsigned short)(pk23 >> 16);
            }
        }
        s16x8 pa[2][2], vb[2][2];
        #pragma unroll
        for (int ni = 0; ni < 2; ++ni)
            #pragma unroll
            for (int k2 = 0; k2 < 2; ++k2)
                pa[ni][k2] = *(const s16x8*)&Psm[w][(ni * 16 + lo) * 72 + k2 * 32 + h4 * 8];
        #pragma unroll
        for (int di = 0; di < 2; ++di)
            #pragma unroll
            for (int k2 = 0; k2 < 2; ++k2)
                vb[di][k2] = *(const s16x8*)&Vsm[(di * 16 + lo) * 72 + k2 * 32 + h4 * 8];
        #pragma unroll
        for (int k2 = 0; k2 < 2; ++k2)
            #pragma unroll
            for (int ni = 0; ni < 2; ++ni)
                #pragma unroll
                for (int di = 0; di < 2; ++di)
                    acc[ni][di] = __builtin_amdgcn_mfma_f32_16x16x32_bf16(
                        pa[ni][k2], vb[di][k2], acc[ni][di], 0, 0, 0);
        __syncthreads();                      // reads done before next staging write
    }
    #pragma unroll
    for (int ni = 0; ni < 2; ++ni)
        #pragma unroll
        for (int r = 0; r < 4; ++r) {
            float v2 = lp[ni][r];
            v2 += __shfl_xor(v2, 1); v2 += __shfl_xor(v2, 2);
            v2 += __shfl_xor(v2, 4); v2 += __shfl_xor(v2, 8);
            lp[ni][r] = v2;                 // partial row denominator (this m-quarter)
        }
    unsigned short* myctx = pctx + (long)mh * (N_NODES * HIDDEN);
    float* myplp = plp  + (long)(mh * 8 + hh) * N_NODES;
    if (lo == 0)
        #pragma unroll
        for (int ni = 0; ni < 2; ++ni)
            #pragma unroll
            for (int r = 0; r < 4; ++r)
                myplp[n0 + ni * 16 + h4 * 4 + r] = lp[ni][r];
    #pragma unroll
    for (int ni = 0; ni < 2; ++ni)
        #pragma unroll
        for (int di = 0; di < 2; ++di)
            #pragma unroll
            for (int r = 0; r < 4; ++r)
                myctx[(long)(n0 + ni * 16 + h4 * 4 + r) * HIDDEN + hh * 32 + di * 16 + lo]
                    = f2bf(acc[ni][di][r]);
}

extern "C" void kernel_launch(void* const* d_in, const int* in_sizes, int n_in,
                              void* d_out, int out_size, void* d_ws, size_t ws_size,
                              hipStream_t stream)
{
    const float* q  = (const float*)d_in[0];
    const float* k  = (const float*)d_in[1];
    const float* v  = (const float*)d_in[2];
    const float* T  = (const float*)d_in[3];
    const float* Wq = (const float*)d_in[4];  const float* bq = (const float*)d_in[5];
    const float* Wk = (const float*)d_in[6];  const float* bk = (const float*)d_in[7];
    const float* Wv = (const float*)d_in[8];  const float* bv = (const float*)d_in[9];
    const float* Wo = (const float*)d_in[10]; const float* bo = (const float*)d_in[11];

    char* w = (char*)d_ws;
    unsigned short* qh_t = (unsigned short*)(w);                     // [256][16384] bf16, 8 MB
    unsigned short* kh   = (unsigned short*)(w + (8u  << 20));       // [4096][256]  bf16, 2 MB
    unsigned short* vh_t = (unsigned short*)(w + (10u << 20));       // [256][4096]  bf16, 2 MB
    unsigned short* qn   = (unsigned short*)(w + (12u << 20));       // [4096][256]  bf16, 2 MB
    unsigned short* pctx = (unsigned short*)(w + (14u << 20));       // [4][4096][256] bf16, 8 MB
    float*          plp  = (float*)         (w + (22u << 20));       // [4][8][4096] f32, 512 KB
    unsigned short* part = (unsigned short*)(w + (23u << 20));       // [16][4096][256] bf16, 32 MB
    float*          rsp  = (float*)         (w + (55u << 20));       // [16][4096]   f32, 256 KB

    proj_all<<<768, 256, 0, stream>>>(q, k, v, Wq, bq, Wk, bk, Wv, bv, qh_t, kh, vh_t);
    tgemm<<<512, 512, 0, stream>>>(T, qh_t, part, rsp);
    finalize<<<1024, 256, 0, stream>>>(part, rsp, qn);
    attn<<<1024, 256, 0, stream>>>(qn, kh, vh_t, pctx, plp);
    proj_out_mfma<<<dim3(64, 4), 256, 0, stream>>>(pctx, plp, Wo, bo, (float*)d_out);
}

// Round 21
// 185.864 us; speedup vs baseline: 1.1540x; 1.1540x over previous
//
#include <hip/hip_runtime.h>

// Node_Edge_Switch_Attention on MI355X (gfx950)
// FINAL = R19 (186.1us, absmax 9.77e-4). R20's proj_all+in-reg-W merge regressed
//   (+28us: per-use W conversion in latency-bound kernels + 3-body code bloat);
//   reverted per pre-commitment.
// Pipeline: cvtW | proj_q (MODE2, A-reuse x2, LDS-transpose stores) | proj_kv
//   (merged k MODE1 + v MODE2) | tgemm (128-row tile, split-K=16, counted-vmcnt,
//   bf16 partials) | finalize | attn (m-split x4, K/V reg-prefetch, cvt_pk P,
//   bf16 pctx) | proj_out (4-way partial merge).

#define N_NODES 4096
#define N_EDGES 16384
#define HIDDEN  256
#define KSPLIT  16

typedef __attribute__((ext_vector_type(4))) float f32x4;
typedef __attribute__((ext_vector_type(8))) short s16x8;          // 8 bf16 (4 VGPRs)
typedef __attribute__((ext_vector_type(4))) unsigned short u16x4;
typedef __attribute__((ext_vector_type(8))) unsigned short u16x8;

__device__ __forceinline__ unsigned short f2bf(float f) {
    union { float f; unsigned u; } x; x.f = f;
    unsigned r = x.u + 0x7FFFu + ((x.u >> 16) & 1u);   // RTNE (values finite here)
    return (unsigned short)(r >> 16);
}
__device__ __forceinline__ float bf2f(unsigned short u) {
    union { unsigned u; float f; } x; x.u = (unsigned)u << 16; return x.f;
}
__device__ __forceinline__ s16x8 pack8s(f32x4 x, f32x4 y) {
    u16x8 o;
    o[0]=f2bf(x[0]); o[1]=f2bf(x[1]); o[2]=f2bf(x[2]); o[3]=f2bf(x[3]);
    o[4]=f2bf(y[0]); o[5]=f2bf(y[1]); o[6]=f2bf(y[2]); o[7]=f2bf(y[3]);
    union { u16x8 u; s16x8 s; } c; c.u = o; return c.s;
}

// ---------------- W -> bf16 (Wq|Wk|Wv|Wo concatenated into dst[4][65536]) ----------
__global__ __launch_bounds__(256)
void cvtW(const float* __restrict__ Wq, const float* __restrict__ Wk,
          const float* __restrict__ Wv, const float* __restrict__ Wo,
          unsigned short* __restrict__ dst)
{
    const int g = blockIdx.x * 256 + threadIdx.x;      // 32768 threads x 8 elems
    const long base = (long)g * 8;
    const int mat = (int)(base >> 16), off = (int)(base & 65535);
    const float* src = (mat == 0) ? Wq : (mat == 1) ? Wk : (mat == 2) ? Wv : Wo;
    f32x4 x = *(const f32x4*)&src[off];
    f32x4 y = *(const f32x4*)&src[off + 4];
    union { u16x8 u; s16x8 s; } c; c.s = pack8s(x, y);
    *(u16x8*)&dst[base] = c.u;
}

// ---------------- shared projection core ---------------------------------------------
// Computes one 64(m) x 128(n) tile: af loaded once, bn-loop of 2. Epilogue mode 1 or 2.
template<int MODE>
__device__ __forceinline__
void proj_body(const float* __restrict__ A, const unsigned short* __restrict__ Wbf,
               const float* __restrict__ bias, unsigned short* __restrict__ out,
               int M, int mb, int ny)
{
    __shared__ __align__(16) unsigned short Tt[64][68];   // MODE2 transpose tile
    const int t = threadIdx.x;
    const int w = t >> 6, l = t & 63, lo = l & 15, h4 = l >> 4;
    const int m0 = mb + w * 16;
    const float* Ar = A + (long)(m0 + lo) * 256 + h4 * 8;

    s16x8 af[8];
    #pragma unroll
    for (int kk = 0; kk < 8; ++kk) {
        f32x4 x = *(const f32x4*)&Ar[kk * 32];
        f32x4 y = *(const f32x4*)&Ar[kk * 32 + 4];
        af[kk] = pack8s(x, y);
    }
    #pragma unroll
    for (int bi = 0; bi < 2; ++bi) {
        const int bn = ny * 128 + bi * 64;
        f32x4 acc[4] = {};
        #pragma unroll
        for (int kk = 0; kk < 8; ++kk)
            #pragma unroll
            for (int nj = 0; nj < 4; ++nj) {
                s16x8 bf = *(const s16x8*)&Wbf[(bn + nj * 16 + lo) * 256 + kk * 32 + h4 * 8];
                acc[nj] = __builtin_amdgcn_mfma_f32_16x16x32_bf16(af[kk], bf, acc[nj], 0, 0, 0);
            }
        if (MODE == 1) {
            #pragma unroll
            for (int nj = 0; nj < 4; ++nj) {
                const int n = bn + nj * 16 + lo;
                const float bi_ = bias[n];
                #pragma unroll
                for (int r = 0; r < 4; ++r)
                    out[(long)(m0 + h4 * 4 + r) * 256 + n] = f2bf(acc[nj][r] + bi_);
            }
        } else {
            if (bi) __syncthreads();                   // prior tile's reads done
            #pragma unroll
            for (int nj = 0; nj < 4; ++nj) {
                const int nl = nj * 16 + lo;
                const float bi_ = bias[bn + nl];
                u16x4 o;
                #pragma unroll
                for (int r = 0; r < 4; ++r) o[r] = f2bf(acc[nj][r] + bi_);
                *(u16x4*)&Tt[nl][w * 16 + h4 * 4] = o;
            }
            __syncthreads();                           // tile complete in LDS
            const int row = t >> 2, seg = (t & 3) * 16;
            u16x8 lo8 = *(const u16x8*)&Tt[row][seg];
            u16x8 hi8 = *(const u16x8*)&Tt[row][seg + 8];
            unsigned short* dst = &out[(long)(bn + row) * M + mb + seg];
            *(u16x8*)dst        = lo8;
            *(u16x8*)(dst + 8)  = hi8;
        }
    }
}

// q projection (MODE2), grid (M/64, 2)
__global__ __launch_bounds__(256)
void proj_q(const float* __restrict__ A, const unsigned short* __restrict__ Wbf,
            const float* __restrict__ bias, unsigned short* __restrict__ out, int M)
{
    proj_body<2>(A, Wbf, bias, out, M, blockIdx.x * 64, blockIdx.y);
}

// merged k (MODE1) + v (MODE2) projection, grid (64, 4): y>>1 = matrix, y&1 = bn half
__global__ __launch_bounds__(256)
void proj_kv(const float* __restrict__ k, const float* __restrict__ v,
             const unsigned short* __restrict__ Wkbf, const unsigned short* __restrict__ Wvbf,
             const float* __restrict__ bk, const float* __restrict__ bv,
             unsigned short* __restrict__ kh, unsigned short* __restrict__ vh_t)
{
    const int ny = blockIdx.y & 1;
    if ((blockIdx.y >> 1) == 0)
        proj_body<1>(k, Wkbf, bk, kh,   N_NODES, blockIdx.x * 64, ny);
    else
        proj_body<2>(v, Wvbf, bv, vh_t, N_NODES, blockIdx.x * 64, ny);
}

// ---------------- out-proj MFMA, 4-way merge from bf16 pctx -------------------------
__global__ __launch_bounds__(256)
void proj_out_mfma(const unsigned short* __restrict__ pctx, const float* __restrict__ plp,
                   const unsigned short* __restrict__ Wobf, const float* __restrict__ bo,
                   float* __restrict__ out)
{
    const int t = threadIdx.x;
    const int w = t >> 6, l = t & 63, lo = l & 15, h4 = l >> 4;
    const int m0 = blockIdx.x * 64 + w * 16;
    const int bn = blockIdx.y * 64;
    const int m = m0 + lo;

    float inv[8];
    #pragma unroll
    for (int h = 0; h < 8; ++h) {
        float s = plp[(0 * 8 + h) * N_NODES + m] + plp[(1 * 8 + h) * N_NODES + m]
                + plp[(2 * 8 + h) * N_NODES + m] + plp[(3 * 8 + h) * N_NODES + m];
        inv[h] = 1.0f / s;
    }
    const unsigned short* P = pctx + (long)m * 256;
    const long PS = (long)N_NODES * 256;

    f32x4 acc[4] = {};
    #pragma unroll
    for (int kk = 0; kk < 8; ++kk) {
        const int off = kk * 32 + h4 * 8;
        f32x4 x = {}, y = {};
        #pragma unroll
        for (int p = 0; p < 4; ++p) {
            u16x8 v = *(const u16x8*)&P[p * PS + off];
            #pragma unroll
            for (int i = 0; i < 4; ++i) { x[i] += bf2f(v[i]); y[i] += bf2f(v[i + 4]); }
        }
        s16x8 af = pack8s(x * inv[kk], y * inv[kk]);
        #pragma unroll
        for (int nj = 0; nj < 4; ++nj) {
            s16x8 bf = *(const s16x8*)&Wobf[(bn + nj * 16 + lo) * 256 + kk * 32 + h4 * 8];
            acc[nj] = __builtin_amdgcn_mfma_f32_16x16x32_bf16(af, bf, acc[nj], 0, 0, 0);
        }
    }
    #pragma unroll
    for (int nj = 0; nj < 4; ++nj) {
        const int n = bn + nj * 16 + lo;
        const float bi = bo[n];
        #pragma unroll
        for (int r = 0; r < 4; ++r)
            out[(long)(m0 + h4 * 4 + r) * 256 + n] = acc[nj][r] + bi;
    }
}

// ---------------- T @ qh_t^T : 128-row tile, split-K=16, counted-vmcnt --------------
__global__ __launch_bounds__(512, 4)
void tgemm(const float* __restrict__ T, const unsigned short* __restrict__ Bt,
           unsigned short* __restrict__ part, float* __restrict__ rsp)
{
    __shared__ __align__(16) unsigned short Bsm[2][256 * 64];   // 32 KB each
    const int t  = threadIdx.x;
    const int ks = blockIdx.x & 15, ms = blockIdx.x >> 4;
    const int m0 = ms * 128;
    const long k00 = (long)ks * 1024;
    const int w = t >> 6, l = t & 63, lo = l & 15, h4 = l >> 4;

    const int kx = ((l & 7) * 8) ^ ((l >> 3) << 3);            // ushort units
    const unsigned short* Bsrc = Bt + k00 + kx;

#define STAGE(itv, bufv) do {                                                       \
    const unsigned short* _s = Bsrc + (long)(itv) * 64;                             \
    unsigned short* _d = &Bsm[(bufv)][w * 2048];                                    \
    _Pragma("unroll")                                                               \
    for (int _i = 0; _i < 4; ++_i)                                                  \
        __builtin_amdgcn_global_load_lds(                                           \
            (const __attribute__((address_space(1))) unsigned int*)                 \
                (_s + (long)(w * 32 + _i * 8 + (l >> 3)) * N_EDGES),                \
            (__attribute__((address_space(3))) unsigned int*)(_d + _i * 512),       \
            16, 0, 0);                                                              \
} while (0)

    const float* Arow = T + (long)(m0 + w * 16 + lo) * N_EDGES + k00 + h4 * 8;

    f32x4 a0 = *(const f32x4*)&Arow[0];
    f32x4 a1 = *(const f32x4*)&Arow[4];
    f32x4 a2 = *(const f32x4*)&Arow[32];
    f32x4 a3 = *(const f32x4*)&Arow[36];
    STAGE(0, 0);

    f32x4 acc[16] = {};
    float rs = 0.f;

    for (int it = 0; it < 16; ++it) {
        const int cur = it & 1;
        __builtin_amdgcn_s_barrier();                // WAR: all waves done reading buf cur^1
        if (it < 15) {
            STAGE(it + 1, cur ^ 1);                  // 4 VMEM (newest)
            asm volatile("s_waitcnt vmcnt(4)" ::: "memory");   // stage(it)+A(it) landed
        } else {
            asm volatile("s_waitcnt vmcnt(0)" ::: "memory");   // final iter: full drain
        }
        s16x8 af0 = pack8s(a0, a1);                  // consume a BEFORE overwrite
        s16x8 af1 = pack8s(a2, a3);
        rs += a0[0]+a0[1]+a0[2]+a0[3] + a1[0]+a1[1]+a1[2]+a1[3]
            + a2[0]+a2[1]+a2[2]+a2[3] + a3[0]+a3[1]+a3[2]+a3[3];
        if (it < 15) {                               // A prefetch (4 VMEM, same bank)
            const float* An = Arow + (it + 1) * 64;
            a0 = *(const f32x4*)&An[0];
            a1 = *(const f32x4*)&An[4];
            a2 = *(const f32x4*)&An[32];
            a3 = *(const f32x4*)&An[36];
        }
        __builtin_amdgcn_s_barrier();                // RAW: every wave's stage(it) in LDS
        __builtin_amdgcn_sched_barrier(0);           // no ds_read hoisted above barrier

        const unsigned short* Bb = Bsm[cur];
        const int swz = (lo & 7) << 3;               // ushort units
        #pragma unroll
        for (int nj = 0; nj < 16; ++nj) {
            const int jb = (nj * 16 + lo) * 64;
            s16x8 bf0 = *(const s16x8*)&Bb[jb + ((h4 * 8) ^ swz)];
            s16x8 bf1 = *(const s16x8*)&Bb[jb + ((32 + h4 * 8) ^ swz)];
            acc[nj] = __builtin_amdgcn_mfma_f32_16x16x32_bf16(af0, bf0, acc[nj], 0, 0, 0);
            acc[nj] = __builtin_amdgcn_mfma_f32_16x16x32_bf16(af1, bf1, acc[nj], 0, 0, 0);
        }
    }
#undef STAGE

    rs += __shfl_xor(rs, 16); rs += __shfl_xor(rs, 32);
    if (h4 == 0) rsp[ks * N_NODES + m0 + w * 16 + lo] = rs;

    unsigned short* P = part + (long)ks * (N_NODES * HIDDEN);
    #pragma unroll
    for (int nj = 0; nj < 16; ++nj)
        #pragma unroll
        for (int r = 0; r < 4; ++r)
            P[(long)(m0 + w * 16 + h4 * 4 + r) * HIDDEN + nj * 16 + lo] = f2bf(acc[nj][r]);
}

// ---------------- finalize: qn = scale * sum_ks(bf16 part) / rowsum -> bf16 ---------
__global__ __launch_bounds__(256)
void finalize(const unsigned short* __restrict__ part, const float* __restrict__ rsp,
              unsigned short* __restrict__ qn)
{
    const int idx = blockIdx.x * 256 + threadIdx.x;    // 262144 groups of 4
    const long i4 = (long)idx * 4;
    const int n = (int)(i4 >> 8);
    f32x4 s = {};
    #pragma unroll
    for (int ksp = 0; ksp < KSPLIT; ++ksp) {
        u16x4 p = *(const u16x4*)&part[(long)ksp * (N_NODES * HIDDEN) + i4];
        #pragma unroll
        for (int i = 0; i < 4; ++i) s[i] += bf2f(p[i]);
    }
    float rs = 0.f;
    #pragma unroll
    for (int ksp = 0; ksp < KSPLIT; ++ksp) rs += rsp[ksp * N_NODES + n];
    rs = (rs == 0.0f) ? 1.0f : rs;                    // reference zero-row guard
    const float sc = 0.17677669529663687f / rs;       // 32^-0.5
    u16x4 o;
    #pragma unroll
    for (int i = 0; i < 4; ++i) o[i] = f2bf(s[i] * sc);
    *(u16x4*)&qn[i4] = o;
}

// ---------------- attention, m-split x4, K/V reg-prefetch, cvt_pk P, bf16 pctx ------
__global__ __launch_bounds__(256)
void attn(const unsigned short* __restrict__ qn, const unsigned short* __restrict__ kh,
          const unsigned short* __restrict__ vht, unsigned short* __restrict__ pctx,
          float* __restrict__ plp)
{
    __shared__ __align__(16) unsigned short Ksm[64 * 40];       // 80B rows
    __shared__ __align__(16) unsigned short Vsm[32 * 72];       // 144B rows
    __shared__ __align__(16) unsigned short Psm[4][32 * 72];    // per-wave P (bf16)
    const int t  = threadIdx.x;
    const int hh = blockIdx.x >> 7, nb = (blockIdx.x >> 2) & 31, mh = blockIdx.x & 3;
    const int w = t >> 6, l = t & 63, lo = l & 15, h4 = l >> 4;
    const int n0 = nb * 128 + w * 32;

    const int km = t >> 2, kdc = (t & 3) * 8;
    const int vd = t >> 3, vmc = (t & 7) * 8;

    s16x8 qf[2];
    #pragma unroll
    for (int ni = 0; ni < 2; ++ni)
        qf[ni] = *(const s16x8*)&qn[(long)(n0 + ni * 16 + lo) * HIDDEN + hh * 32 + h4 * 8];

    const unsigned short* kp = &kh[(long)(mh * 1024 + km) * HIDDEN + hh * 32 + kdc];
    const unsigned short* vp = &vht[(long)(hh * 32 + vd) * N_NODES + mh * 1024 + vmc];
    s16x8 kreg = *(const s16x8*)kp;
    s16x8 vreg = *(const s16x8*)vp;

    f32x4 acc[2][2] = {};
    float lp[2][4] = {};
    const f32x4 zero = {};

    for (int it = 0; it < 16; ++it) {
        *(s16x8*)&Ksm[km * 40 + kdc] = kreg;
        *(s16x8*)&Vsm[vd * 72 + vmc] = vreg;
        __syncthreads();                      // staging writes visible
        if (it < 15) {                        // prefetch next tile under compute
            kreg = *(const s16x8*)(kp + (long)(it + 1) * 64 * HIDDEN);
            vreg = *(const s16x8*)(vp + (it + 1) * 64);
        }

        s16x8 kb[4];
        #pragma unroll
        for (int mi = 0; mi < 4; ++mi)
            kb[mi] = *(const s16x8*)&Ksm[(mi * 16 + lo) * 40 + h4 * 8];
        #pragma unroll
        for (int ni = 0; ni < 2; ++ni) {
            #pragma unroll
            for (int mi = 0; mi < 4; ++mi) {
                f32x4 s = __builtin_amdgcn_mfma_f32_16x16x32_bf16(qf[ni], kb[mi], zero, 0, 0, 0);
                float p0 = __expf(s[0]), p1 = __expf(s[1]);
                float p2 = __expf(s[2]), p3 = __expf(s[3]);
                lp[ni][0] += p0; lp[ni][1] += p1; lp[ni][2] += p2; lp[ni][3] += p3;
                unsigned pk01, pk23;                  // RTNE, identical to f2bf
                asm("v_cvt_pk_bf16_f32 %0, %1, %2" : "=v"(pk01) : "v"(p0), "v"(p1));
                asm("v_cvt_pk_bf16_f32 %0, %1, %2" : "=v"(pk23) : "v"(p2), "v"(p3));
                const int pb = (ni * 16 + h4 * 4) * 72 + mi * 16 + lo;
                Psm[w][pb]           = (unsigned short)(pk01 & 0xffffu);
                Psm[w][pb + 72]      = (unsigned short)(pk01 >> 16);
                Psm[w][pb + 144]     = (unsigned short)(pk23 & 0xffffu);
                Psm[w][pb + 216]     = (unsigned short)(pk23 >> 16);
            }
        }
        s16x8 pa[2][2], vb[2][2];
        #pragma unroll
        for (int ni = 0; ni < 2; ++ni)
            #pragma unroll
            for (int k2 = 0; k2 < 2; ++k2)
                pa[ni][k2] = *(const s16x8*)&Psm[w][(ni * 16 + lo) * 72 + k2 * 32 + h4 * 8];
        #pragma unroll
        for (int di = 0; di < 2; ++di)
            #pragma unroll
            for (int k2 = 0; k2 < 2; ++k2)
                vb[di][k2] = *(const s16x8*)&Vsm[(di * 16 + lo) * 72 + k2 * 32 + h4 * 8];
        #pragma unroll
        for (int k2 = 0; k2 < 2; ++k2)
            #pragma unroll
            for (int ni = 0; ni < 2; ++ni)
                #pragma unroll
                for (int di = 0; di < 2; ++di)
                    acc[ni][di] = __builtin_amdgcn_mfma_f32_16x16x32_bf16(
                        pa[ni][k2], vb[di][k2], acc[ni][di], 0, 0, 0);
        __syncthreads();                      // reads done before next staging write
    }
    #pragma unroll
    for (int ni = 0; ni < 2; ++ni)
        #pragma unroll
        for (int r = 0; r < 4; ++r) {
            float v2 = lp[ni][r];
            v2 += __shfl_xor(v2, 1); v2 += __shfl_xor(v2, 2);
            v2 += __shfl_xor(v2, 4); v2 += __shfl_xor(v2, 8);
            lp[ni][r] = v2;                 // partial row denominator (this m-quarter)
        }
    unsigned short* myctx = pctx + (long)mh * (N_NODES * HIDDEN);
    float* myplp = plp  + (long)(mh * 8 + hh) * N_NODES;
    if (lo == 0)
        #pragma unroll
        for (int ni = 0; ni < 2; ++ni)
            #pragma unroll
            for (int r = 0; r < 4; ++r)
                myplp[n0 + ni * 16 + h4 * 4 + r] = lp[ni][r];
    #pragma unroll
    for (int ni = 0; ni < 2; ++ni)
        #pragma unroll
        for (int di = 0; di < 2; ++di)
            #pragma unroll
            for (int r = 0; r < 4; ++r)
                myctx[(long)(n0 + ni * 16 + h4 * 4 + r) * HIDDEN + hh * 32 + di * 16 + lo]
                    = f2bf(acc[ni][di][r]);
}

extern "C" void kernel_launch(void* const* d_in, const int* in_sizes, int n_in,
                              void* d_out, int out_size, void* d_ws, size_t ws_size,
                              hipStream_t stream)
{
    const float* q  = (const float*)d_in[0];
    const float* k  = (const float*)d_in[1];
    const float* v  = (const float*)d_in[2];
    const float* T  = (const float*)d_in[3];
    const float* Wq = (const float*)d_in[4];  const float* bq = (const float*)d_in[5];
    const float* Wk = (const float*)d_in[6];  const float* bk = (const float*)d_in[7];
    const float* Wv = (const float*)d_in[8];  const float* bv = (const float*)d_in[9];
    const float* Wo = (const float*)d_in[10]; const float* bo = (const float*)d_in[11];

    char* w = (char*)d_ws;
    unsigned short* qh_t = (unsigned short*)(w);                     // [256][16384] bf16, 8 MB
    unsigned short* kh   = (unsigned short*)(w + (8u  << 20));       // [4096][256]  bf16, 2 MB
    unsigned short* vh_t = (unsigned short*)(w + (10u << 20));       // [256][4096]  bf16, 2 MB
    unsigned short* qn   = (unsigned short*)(w + (12u << 20));       // [4096][256]  bf16, 2 MB
    unsigned short* pctx = (unsigned short*)(w + (14u << 20));       // [4][4096][256] bf16, 8 MB
    float*          plp  = (float*)         (w + (22u << 20));       // [4][8][4096] f32, 512 KB
    unsigned short* part = (unsigned short*)(w + (23u << 20));       // [16][4096][256] bf16, 32 MB
    float*          rsp  = (float*)         (w + (55u << 20));       // [16][4096]   f32, 256 KB
    unsigned short* wbf  = (unsigned short*)(w + (56u << 20));       // [4][65536]   bf16, 512 KB
    unsigned short* wq_bf = wbf;
    unsigned short* wk_bf = wbf + 65536;
    unsigned short* wv_bf = wbf + 2 * 65536;
    unsigned short* wo_bf = wbf + 3 * 65536;

    cvtW<<<128, 256, 0, stream>>>(Wq, Wk, Wv, Wo, wbf);
    proj_q<<<dim3(256, 2), 256, 0, stream>>>(q, wq_bf, bq, qh_t, N_EDGES);
    proj_kv<<<dim3(64, 4), 256, 0, stream>>>(k, v, wk_bf, wv_bf, bk, bv, kh, vh_t);
    tgemm<<<512, 512, 0, stream>>>(T, qh_t, part, rsp);
    finalize<<<1024, 256, 0, stream>>>(part, rsp, qn);
    attn<<<1024, 256, 0, stream>>>(qn, kh, vh_t, pctx, plp);
    proj_out_mfma<<<dim3(64, 4), 256, 0, stream>>>(pctx, plp, wo_bf, bo, (float*)d_out);
}